// Round 1
// baseline (1590.227 us; speedup 1.0000x reference)
//
#include <hip/hip_runtime.h>
#include <hip/hip_bf16.h>

// Problem: N=16384, G=16.
// cut_loss  = sum_g (Gamma[g] - q[g]) / Gamma[g],  Gamma = Y^T D, q[g] = y_g^T A y_g
// balance   = sum_g (colsum(Y)[g] - N/G)^2
// Single pass over A (1.07 GB) computing t[n,:] = (A Y)[n,:] and D[n] per row.

#define NROWS 16384
#define NCOLS 16384
#define NG 16
#define TILE_M 512               // Y rows staged per LDS tile
#define ROWS_PER_BLOCK 16        // 4 waves x 4 rows
#define NBLOCKS (NROWS / ROWS_PER_BLOCK)

__global__ __launch_bounds__(256) void cut_main_kernel(
    const float* __restrict__ Y, const float* __restrict__ A,
    float* __restrict__ ws) {
  __shared__ float ys[TILE_M * NG];      // 32 KB Y tile, [m_local][g]
  __shared__ float wred[4 * 68];         // per-wave reduced t[4][16] + d[4]
  __shared__ float gacc[48];             // block-level gamma/q/colsum accum

  const int tid = threadIdx.x;
  const int wave = tid >> 6;
  const int lane = tid & 63;
  const int row0 = blockIdx.x * ROWS_PER_BLOCK + wave * 4;

  float acc[4][NG];
  float dsum[4];
#pragma unroll
  for (int r = 0; r < 4; ++r) {
    dsum[r] = 0.f;
#pragma unroll
    for (int g = 0; g < NG; ++g) acc[r][g] = 0.f;
  }

  const float4* __restrict__ Y4 = (const float4*)Y;
  const float4* __restrict__ A4 = (const float4*)A;
  float4* ys4 = (float4*)ys;

  // Per-row base pointers (row stride = 16384 floats = 4096 float4)
  const float4* __restrict__ Ar0 = A4 + (size_t)(row0 + 0) * (NCOLS / 4);
  const float4* __restrict__ Ar1 = A4 + (size_t)(row0 + 1) * (NCOLS / 4);
  const float4* __restrict__ Ar2 = A4 + (size_t)(row0 + 2) * (NCOLS / 4);
  const float4* __restrict__ Ar3 = A4 + (size_t)(row0 + 3) * (NCOLS / 4);

  for (int t = 0; t < NCOLS / TILE_M; ++t) {
    const int m0 = t * TILE_M;
    __syncthreads();
    // Stage Y[m0 : m0+512, 0:16] -> ys. 2048 float4s, 8 per thread, coalesced.
#pragma unroll
    for (int j = 0; j < 8; ++j) {
      ys4[tid + j * 256] = Y4[m0 * (NG / 4) + tid + j * 256];
    }
    __syncthreads();

#pragma unroll
    for (int k = 0; k < 2; ++k) {
      const int mq = lane * 4 + k * 256;          // local column (multiple of 4)
      const int mi = (m0 >> 2) + lane + k * 64;   // float4 index into A row
      float4 av[4];
      av[0] = Ar0[mi];
      av[1] = Ar1[mi];
      av[2] = Ar2[mi];
      av[3] = Ar3[mi];

#define DO_J(J, COMP)                                                     \
      {                                                                   \
        const float4 y0 = ys4[(mq + J) * 4 + 0];                          \
        const float4 y1 = ys4[(mq + J) * 4 + 1];                          \
        const float4 y2 = ys4[(mq + J) * 4 + 2];                          \
        const float4 y3 = ys4[(mq + J) * 4 + 3];                          \
        _Pragma("unroll")                                                 \
        for (int r = 0; r < 4; ++r) {                                     \
          const float a = av[r].COMP;                                     \
          dsum[r] += a;                                                   \
          acc[r][0]  += a * y0.x; acc[r][1]  += a * y0.y;                 \
          acc[r][2]  += a * y0.z; acc[r][3]  += a * y0.w;                 \
          acc[r][4]  += a * y1.x; acc[r][5]  += a * y1.y;                 \
          acc[r][6]  += a * y1.z; acc[r][7]  += a * y1.w;                 \
          acc[r][8]  += a * y2.x; acc[r][9]  += a * y2.y;                 \
          acc[r][10] += a * y2.z; acc[r][11] += a * y2.w;                 \
          acc[r][12] += a * y3.x; acc[r][13] += a * y3.y;                 \
          acc[r][14] += a * y3.z; acc[r][15] += a * y3.w;                 \
        }                                                                 \
      }
      DO_J(0, x)
      DO_J(1, y)
      DO_J(2, z)
      DO_J(3, w)
#undef DO_J
    }
  }

  // Wave-level butterfly reduction of 68 values (one-time cost ~400 ops)
#pragma unroll
  for (int r = 0; r < 4; ++r) {
#pragma unroll
    for (int g = 0; g < NG; ++g) {
      float v = acc[r][g];
      v += __shfl_xor(v, 32);
      v += __shfl_xor(v, 16);
      v += __shfl_xor(v, 8);
      v += __shfl_xor(v, 4);
      v += __shfl_xor(v, 2);
      v += __shfl_xor(v, 1);
      acc[r][g] = v;
    }
    float d = dsum[r];
    d += __shfl_xor(d, 32);
    d += __shfl_xor(d, 16);
    d += __shfl_xor(d, 8);
    d += __shfl_xor(d, 4);
    d += __shfl_xor(d, 2);
    d += __shfl_xor(d, 1);
    dsum[r] = d;
  }

  __syncthreads();  // ys no longer needed; wred/gacc phase
  if (lane == 0) {
#pragma unroll
    for (int r = 0; r < 4; ++r) {
#pragma unroll
      for (int g = 0; g < NG; ++g) wred[wave * 68 + r * 16 + g] = acc[r][g];
      wred[wave * 68 + 64 + r] = dsum[r];
    }
  }
  if (tid < 48) gacc[tid] = 0.f;
  __syncthreads();

  // 256 threads -> 16 rows x 16 groups; accumulate gamma/q/colsum into LDS
  {
    const int row_local = tid >> 4;
    const int g = tid & 15;
    const int w2 = row_local >> 2;
    const int r2 = row_local & 3;
    const float tval = wred[w2 * 68 + r2 * 16 + g];
    const float dval = wred[w2 * 68 + 64 + r2];
    const float yng = Y[(size_t)(blockIdx.x * ROWS_PER_BLOCK + row_local) * NG + g];
    atomicAdd(&gacc[g], yng * dval);         // Gamma partial
    atomicAdd(&gacc[16 + g], yng * tval);    // q partial
    atomicAdd(&gacc[32 + g], yng);           // colsum partial
  }
  __syncthreads();
  if (tid < 48) atomicAdd(&ws[tid], gacc[tid]);
}

__global__ void cut_finalize_kernel(const float* __restrict__ ws,
                                    float* __restrict__ out) {
  if (threadIdx.x == 0 && blockIdx.x == 0) {
    float cut = 0.f, bal = 0.f;
#pragma unroll
    for (int g = 0; g < NG; ++g) {
      const float gamma = ws[g];
      const float q = ws[16 + g];
      const float col = ws[32 + g];
      cut += (gamma - q) / gamma;
      const float d = col - (float)(NROWS / NG);
      bal += d * d;
    }
    out[0] = cut + bal;
  }
}

extern "C" void kernel_launch(void* const* d_in, const int* in_sizes, int n_in,
                              void* d_out, int out_size, void* d_ws, size_t ws_size,
                              hipStream_t stream) {
  const float* Y = (const float*)d_in[0];   // [16384, 16]
  const float* A = (const float*)d_in[1];   // [16384, 16384]
  float* ws = (float*)d_ws;                 // 48 floats: gamma[16], q[16], colsum[16]
  float* out = (float*)d_out;

  hipMemsetAsync(d_ws, 0, 48 * sizeof(float), stream);
  hipLaunchKernelGGL(cut_main_kernel, dim3(NBLOCKS), dim3(256), 0, stream, Y, A, ws);
  hipLaunchKernelGGL(cut_finalize_kernel, dim3(1), dim3(64), 0, stream, ws, out);
}